// Round 1
// baseline (1052.112 us; speedup 1.0000x reference)
//
#include <hip/hip_runtime.h>

// QuantLinear: out[T,N] = x[T,K] @ dequant(W)[K,N] + bias
// T=8192, K=4096, N=11008, GROUP=32 (e8m0 scales), fp4 e2m1 nibbles packed 8/int32.
//
// Plan: precompute xbf16 (67MB) and W^T bf16 (90MB) into d_ws, then run a
// 128x128-tile bf16 MFMA GEMM (m97 structure: global_load_lds width 16,
// 2-barrier K-loop). Fallback fused kernel if ws_size too small.

#define TDIM 8192
#define KDIM 4096
#define NDIM 11008

typedef __attribute__((ext_vector_type(8))) short short8;
typedef __attribute__((ext_vector_type(8))) unsigned short ushort8;
typedef __attribute__((ext_vector_type(4))) float f32x4;

__device__ __forceinline__ unsigned short f2bf(float f) {
    unsigned int u = __float_as_uint(f);
    u += 0x7FFFu + ((u >> 16) & 1u);   // round-to-nearest-even
    return (unsigned short)(u >> 16);
}

// fp4 e2m1 nibble + e8m0 exponent -> exact bf16 bits.
// value = sign * mag(m3) * 2^(e-127); mag LUT {0,.5,1,1.5,2,3,4,6}.
// bf16: s<<15 | E<<7 | man.  E = e + (m3>>1) - 1 (works for m3==1 too), man=(m3&1)<<6 iff m3>=2.
__device__ __forceinline__ unsigned short nib2bf(unsigned int v, int e) {
    unsigned int m3 = v & 7u;
    if (m3 == 0u) return 0;
    unsigned int s = (v & 8u) << 12;
    unsigned int E = (unsigned int)e + (m3 >> 1) - 1u;
    unsigned int man = (m3 >= 2u) ? ((m3 & 1u) << 6) : 0u;
    return (unsigned short)(s | (E << 7) | man);
}

__device__ __forceinline__ void gload_lds16(const void* g, void* l) {
    __builtin_amdgcn_global_load_lds(
        (const __attribute__((address_space(1))) void*)g,
        (__attribute__((address_space(3))) void*)l, 16, 0, 0);
}

// ---------------- pre-pass 1: x fp32 -> bf16 ----------------
__global__ __launch_bounds__(256) void convert_x(const float* __restrict__ x,
                                                 unsigned short* __restrict__ xbf) {
    size_t i = ((size_t)blockIdx.x * 256 + threadIdx.x) * 8;
    float4 v0 = *(const float4*)(x + i);
    float4 v1 = *(const float4*)(x + i + 4);
    ushort8 r;
    r[0] = f2bf(v0.x); r[1] = f2bf(v0.y); r[2] = f2bf(v0.z); r[3] = f2bf(v0.w);
    r[4] = f2bf(v1.x); r[5] = f2bf(v1.y); r[6] = f2bf(v1.z); r[7] = f2bf(v1.w);
    *(ushort8*)(xbf + i) = r;
}

// ---------------- pre-pass 2: dequant W -> W^T bf16 [N][K] ----------------
// Tile: 64 packed rows (512 k) x 64 cols. LDS transpose so both global read
// (along n) and global write (along k) are coalesced.
__global__ __launch_bounds__(256) void dequant_w(const int* __restrict__ wp,
                                                 const int* __restrict__ wse,
                                                 unsigned short* __restrict__ wt) {
    __shared__ int sT[64][65];  // +1 pad: conflict-free column reads
    const int tid = threadIdx.x;
    const int n0 = blockIdx.x * 64;   // 172 tiles
    const int r0 = blockIdx.y * 64;   // 8 tiles (packed rows)

    #pragma unroll
    for (int i = 0; i < 16; ++i) {
        int idx = i * 256 + tid;
        int r = idx >> 6, n = idx & 63;
        sT[r][n] = wp[(size_t)(r0 + r) * NDIM + n0 + n];
    }
    __syncthreads();
    #pragma unroll
    for (int i = 0; i < 16; ++i) {
        int idx = i * 256 + tid;
        int n = idx >> 6, r = idx & 63;   // lanes sweep r -> contiguous k writes
        unsigned int p = (unsigned int)sT[r][n];
        int e = wse[(size_t)((r0 + r) >> 2) * NDIM + n0 + n];
        ushort8 o;
        #pragma unroll
        for (int j = 0; j < 8; ++j) o[j] = nib2bf((p >> (4 * j)) & 0xFu, e);
        *(ushort8*)(wt + (size_t)(n0 + n) * KDIM + (size_t)(r0 + r) * 8) = o;
    }
}

// ---------------- main GEMM: bf16, 128x128 tile, BK=64, 4 waves ----------------
__global__ __launch_bounds__(256, 2) void gemm_bf16(const unsigned short* __restrict__ xbf,
                                                    const unsigned short* __restrict__ wt,
                                                    const float* __restrict__ bias,
                                                    float* __restrict__ out) {
    __shared__ __attribute__((aligned(16))) unsigned short lA[128 * 64];
    __shared__ __attribute__((aligned(16))) unsigned short lB[128 * 64];
    const int tid = threadIdx.x;
    const int l = tid & 63, wid = tid >> 6;
    const int bn0 = blockIdx.x * 128, bm0 = blockIdx.y * 128;
    const int wm = wid >> 1, wn = wid & 1;

    f32x4 acc[4][4] = {};

    // staging geometry: per wave 4 issues x 1KB; lane l covers row wid*32+i*8+(l>>3), k (l&7)*8..+7
    const int srow = wid * 32 + (l >> 3);
    const int kseg = (l & 7) * 8;
    const unsigned short* aSrc = xbf + (size_t)(bm0 + srow) * KDIM + kseg;
    const unsigned short* bSrc = wt + (size_t)(bn0 + srow) * KDIM + kseg;
    unsigned short* aDst = &lA[wid * 2048];
    unsigned short* bDst = &lB[wid * 2048];

    for (int k0 = 0; k0 < KDIM; k0 += 64) {
        #pragma unroll
        for (int i = 0; i < 4; ++i) {
            gload_lds16(aSrc + k0 + (size_t)i * 8 * KDIM, aDst + i * 512);
            gload_lds16(bSrc + k0 + (size_t)i * 8 * KDIM, bDst + i * 512);
        }
        __syncthreads();
        #pragma unroll
        for (int kc = 0; kc < 2; ++kc) {
            short8 a[4], b[4];
            #pragma unroll
            for (int f = 0; f < 4; ++f) {
                a[f] = *(const short8*)&lA[(wm * 64 + f * 16 + (l & 15)) * 64 + kc * 32 + (l >> 4) * 8];
                b[f] = *(const short8*)&lB[(wn * 64 + f * 16 + (l & 15)) * 64 + kc * 32 + (l >> 4) * 8];
            }
            #pragma unroll
            for (int fm = 0; fm < 4; ++fm)
                #pragma unroll
                for (int fn = 0; fn < 4; ++fn)
                    acc[fm][fn] = __builtin_amdgcn_mfma_f32_16x16x32_bf16(a[fm], b[fn], acc[fm][fn], 0, 0, 0);
        }
        __syncthreads();
    }

    // epilogue: C/D layout col=lane&15, row=(lane>>4)*4+j
    const int crow = (l >> 4) * 4, ccol = l & 15;
    #pragma unroll
    for (int fn = 0; fn < 4; ++fn) {
        int col = bn0 + wn * 64 + fn * 16 + ccol;
        float bv = bias[col];
        #pragma unroll
        for (int fm = 0; fm < 4; ++fm) {
            int row0 = bm0 + wm * 64 + fm * 16 + crow;
            #pragma unroll
            for (int j = 0; j < 4; ++j)
                out[(size_t)(row0 + j) * NDIM + col] = acc[fm][fn][j] + bv;
        }
    }
}

// ---------------- fallback: fused dequant GEMM (if ws too small) ----------------
__global__ __launch_bounds__(256, 2) void gemm_fused(const float* __restrict__ x,
                                                     const int* __restrict__ wp,
                                                     const int* __restrict__ wse,
                                                     const float* __restrict__ bias,
                                                     float* __restrict__ out) {
    __shared__ __attribute__((aligned(16))) unsigned short lA[128 * 64];
    __shared__ __attribute__((aligned(16))) unsigned short lB[128 * 64];
    const int tid = threadIdx.x;
    const int l = tid & 63, wid = tid >> 6;
    const int bn0 = blockIdx.x * 128, bm0 = blockIdx.y * 128;
    const int wm = wid >> 1, wn = wid & 1;

    f32x4 acc[4][4] = {};

    for (int k0 = 0; k0 < KDIM; k0 += 64) {
        float4 av0[4], av1[4];
        unsigned int bp[4];
        int be[4];
        #pragma unroll
        for (int i = 0; i < 4; ++i) {
            int seg = i * 256 + tid;
            int row = seg >> 3, ks = seg & 7;
            const float4* p = (const float4*)(x + (size_t)(bm0 + row) * KDIM + k0 + ks * 8);
            av0[i] = p[0]; av1[i] = p[1];
        }
        #pragma unroll
        for (int i = 0; i < 4; ++i) {
            int idx = i * 256 + tid;
            int ln = idx & 127, lr = idx >> 7;
            bp[i] = ((const unsigned int*)wp)[(size_t)(k0 / 8 + lr) * NDIM + bn0 + ln];
            be[i] = wse[(size_t)((k0 + lr * 8) >> 5) * NDIM + bn0 + ln];
        }
        #pragma unroll
        for (int i = 0; i < 4; ++i) {
            int seg = i * 256 + tid;
            int row = seg >> 3, ks = seg & 7;
            ushort8 r;
            r[0] = f2bf(av0[i].x); r[1] = f2bf(av0[i].y); r[2] = f2bf(av0[i].z); r[3] = f2bf(av0[i].w);
            r[4] = f2bf(av1[i].x); r[5] = f2bf(av1[i].y); r[6] = f2bf(av1[i].z); r[7] = f2bf(av1[i].w);
            *(ushort8*)&lA[row * 64 + ks * 8] = r;
        }
        #pragma unroll
        for (int i = 0; i < 4; ++i) {
            int idx = i * 256 + tid;
            int ln = idx & 127, lr = idx >> 7;
            unsigned int p = bp[i];
            int e = be[i];
            ushort8 r;
            #pragma unroll
            for (int j = 0; j < 8; ++j) r[j] = nib2bf((p >> (4 * j)) & 0xFu, e);
            *(ushort8*)&lB[ln * 64 + lr * 8] = r;
        }
        __syncthreads();
        #pragma unroll
        for (int kc = 0; kc < 2; ++kc) {
            short8 a[4], b[4];
            #pragma unroll
            for (int f = 0; f < 4; ++f) {
                a[f] = *(const short8*)&lA[(wm * 64 + f * 16 + (l & 15)) * 64 + kc * 32 + (l >> 4) * 8];
                b[f] = *(const short8*)&lB[(wn * 64 + f * 16 + (l & 15)) * 64 + kc * 32 + (l >> 4) * 8];
            }
            #pragma unroll
            for (int fm = 0; fm < 4; ++fm)
                #pragma unroll
                for (int fn = 0; fn < 4; ++fn)
                    acc[fm][fn] = __builtin_amdgcn_mfma_f32_16x16x32_bf16(a[fm], b[fn], acc[fm][fn], 0, 0, 0);
        }
        __syncthreads();
    }

    const int crow = (l >> 4) * 4, ccol = l & 15;
    #pragma unroll
    for (int fn = 0; fn < 4; ++fn) {
        int col = bn0 + wn * 64 + fn * 16 + ccol;
        float bv = bias[col];
        #pragma unroll
        for (int fm = 0; fm < 4; ++fm) {
            int row0 = bm0 + wm * 64 + fm * 16 + crow;
            #pragma unroll
            for (int j = 0; j < 4; ++j)
                out[(size_t)(row0 + j) * NDIM + col] = acc[fm][fn][j] + bv;
        }
    }
}

extern "C" void kernel_launch(void* const* d_in, const int* in_sizes, int n_in,
                              void* d_out, int out_size, void* d_ws, size_t ws_size,
                              hipStream_t stream) {
    (void)in_sizes; (void)n_in; (void)out_size;
    const float* x = (const float*)d_in[0];
    const int* wp = (const int*)d_in[1];
    const int* wse = (const int*)d_in[2];
    const float* bias = (const float*)d_in[3];
    float* out = (float*)d_out;

    const size_t xbf_bytes = (size_t)TDIM * KDIM * 2;  // 67.1 MB
    const size_t wt_bytes = (size_t)NDIM * KDIM * 2;   // 90.2 MB

    if (ws_size >= xbf_bytes + wt_bytes) {
        unsigned short* xbf = (unsigned short*)d_ws;
        unsigned short* wt = (unsigned short*)((char*)d_ws + xbf_bytes);
        hipLaunchKernelGGL(convert_x, dim3((TDIM * KDIM) / (256 * 8)), dim3(256), 0, stream, x, xbf);
        hipLaunchKernelGGL(dequant_w, dim3(NDIM / 64, (KDIM / 8) / 64), dim3(256), 0, stream, wp, wse, wt);
        hipLaunchKernelGGL(gemm_bf16, dim3(NDIM / 128, TDIM / 128), dim3(256), 0, stream, xbf, wt, bias, out);
    } else {
        hipLaunchKernelGGL(gemm_fused, dim3(NDIM / 128, TDIM / 128), dim3(256), 0, stream, x, wp, wse, bias, out);
    }
}

// Round 2
// 812.667 us; speedup vs baseline: 1.2946x; 1.2946x over previous
//
#include <hip/hip_runtime.h>

// QuantLinear: out[T,N] = x[T,K] @ dequant(W)[K,N] + bias
// T=8192, K=4096, N=11008. Pre-pass: x->bf16, W->bf16 W^T [N][K] in d_ws.
// Main GEMM: 256x256 tile, BK=64, 8 waves (2Mx4N), 8-phase schedule with
// st_16x32 LDS swizzle (inverse-swizzled global_load_lds source), counted
// vmcnt, setprio around MFMA, XCD-aware block swizzle.

#define TDIM 8192
#define KDIM 4096
#define NDIM 11008

typedef __attribute__((ext_vector_type(8))) short short8;
typedef __attribute__((ext_vector_type(8))) unsigned short ushort8;
typedef __attribute__((ext_vector_type(4))) float f32x4;

__device__ __forceinline__ unsigned short f2bf(float f) {
    unsigned int u = __float_as_uint(f);
    u += 0x7FFFu + ((u >> 16) & 1u);   // round-to-nearest-even
    return (unsigned short)(u >> 16);
}

// fp4 e2m1 nibble + e8m0 exponent -> exact bf16 bits.
__device__ __forceinline__ unsigned short nib2bf(unsigned int v, int e) {
    unsigned int m3 = v & 7u;
    if (m3 == 0u) return 0;
    unsigned int s = (v & 8u) << 12;
    unsigned int E = (unsigned int)e + (m3 >> 1) - 1u;
    unsigned int man = (m3 >= 2u) ? ((m3 & 1u) << 6) : 0u;
    return (unsigned short)(s | (E << 7) | man);
}

__device__ __forceinline__ void gload_lds16(const void* g, void* l) {
    __builtin_amdgcn_global_load_lds(
        (const __attribute__((address_space(1))) void*)g,
        (__attribute__((address_space(3))) void*)l, 16, 0, 0);
}

// ---------------- pre-pass 1: x fp32 -> bf16 ----------------
__global__ __launch_bounds__(256) void convert_x(const float* __restrict__ x,
                                                 unsigned short* __restrict__ xbf) {
    size_t i = ((size_t)blockIdx.x * 256 + threadIdx.x) * 8;
    float4 v0 = *(const float4*)(x + i);
    float4 v1 = *(const float4*)(x + i + 4);
    ushort8 r;
    r[0] = f2bf(v0.x); r[1] = f2bf(v0.y); r[2] = f2bf(v0.z); r[3] = f2bf(v0.w);
    r[4] = f2bf(v1.x); r[5] = f2bf(v1.y); r[6] = f2bf(v1.z); r[7] = f2bf(v1.w);
    *(ushort8*)(xbf + i) = r;
}

// ---------------- pre-pass 2: dequant W -> W^T bf16 [N][K] ----------------
__global__ __launch_bounds__(256) void dequant_w(const int* __restrict__ wp,
                                                 const int* __restrict__ wse,
                                                 unsigned short* __restrict__ wt) {
    __shared__ int sT[64][65];
    const int tid = threadIdx.x;
    const int n0 = blockIdx.x * 64;
    const int r0 = blockIdx.y * 64;

    #pragma unroll
    for (int i = 0; i < 16; ++i) {
        int idx = i * 256 + tid;
        int r = idx >> 6, n = idx & 63;
        sT[r][n] = wp[(size_t)(r0 + r) * NDIM + n0 + n];
    }
    __syncthreads();
    #pragma unroll
    for (int i = 0; i < 16; ++i) {
        int idx = i * 256 + tid;
        int n = idx >> 6, r = idx & 63;
        unsigned int p = (unsigned int)sT[r][n];
        int e = wse[(size_t)((r0 + r) >> 2) * NDIM + n0 + n];
        ushort8 o;
        #pragma unroll
        for (int j = 0; j < 8; ++j) o[j] = nib2bf((p >> (4 * j)) & 0xFu, e);
        *(ushort8*)(wt + (size_t)(n0 + n) * KDIM + (size_t)(r0 + r) * 8) = o;
    }
}

// ---------------- main GEMM: 256x256 tile, BK=64, 8 waves, 8-phase ----------------
// LDS layout per K-tile buffer: A and B each 256x64 bf16, subtiled:
//   byte = khalf*16384 + sub_row*1024 + (r%16)*64 + (k%32)*2, then
//   byte ^= ((r&8)?32:0)  (st_16x32 swizzle)
// Staging writes LINEAR (global_load_lds); global source is inverse-swizzled.
__global__ __launch_bounds__(512, 1) void gemm256(const unsigned short* __restrict__ xbf,
                                                  const unsigned short* __restrict__ wt,
                                                  const float* __restrict__ bias,
                                                  float* __restrict__ out) {
    __shared__ __attribute__((aligned(16))) unsigned short lds[2][2][16384]; // 128 KiB
    const int tid = threadIdx.x;
    const int l = tid & 63, wid = tid >> 6;
    const int wm = wid >> 2, wn = wid & 3;   // 2 x 4 waves; per-wave 128 rows x 64 cols

    // XCD swizzle (nwg = 1376 = 8*172, bijective)
    int swz = (blockIdx.x & 7) * 172 + (blockIdx.x >> 3);
    const int bn0 = (swz % 43) * 256;
    const int bm0 = (swz / 43) * 256;

    // per-thread staging decode for linear-dest chunk -> (row, k-offset) inverse swizzle
    int r_s[2], k_s[2];
    #pragma unroll
    for (int j = 0; j < 2; ++j) {
        int chunk = j * 512 + wid * 64 + l;   // 16B chunk index within 16KB half-tile
        int sr = chunk >> 6;
        int cin = chunk & 63;
        cin ^= ((cin >> 5) & 1) << 1;         // inverse of byte-bit5^=bit9 (16B units)
        r_s[j] = sr * 16 + (cin >> 2);
        k_s[j] = (cin & 3) * 8;
    }

    f32x4 acc[8][4] = {};
    short8 afr[4], bfr[4];

    // stage one half-tile: stream s -> tile s>>2, idx s&3: 0=A.k0 1=B.k0 2=A.k1 3=B.k1
    auto stage = [&](int s) {
        int tau = s >> 2;
        int idx = s & 3;
        int mat = idx & 1, hk = idx >> 1, c = tau & 1;
        const unsigned short* base = mat ? wt : xbf;
        int rb = mat ? bn0 : bm0;
        int kb = tau * 64 + hk * 32;
        #pragma unroll
        for (int j = 0; j < 2; ++j) {
            const unsigned short* src = base + (size_t)(rb + r_s[j]) * KDIM + kb + k_s[j];
            unsigned short* dst = &lds[c][mat][hk * 8192 + (j * 512 + wid * 64) * 8];
            gload_lds16(src, dst);
        }
    };

    // prologue: tile 0 (4 half-tiles) + tile 1's k0 halves
    #pragma unroll
    for (int s = 0; s < 6; ++s) stage(s);
    asm volatile("s_waitcnt vmcnt(4)" ::: "memory");   // tile 0 landed
    __builtin_amdgcn_s_barrier();

    #pragma unroll 2
    for (int t = 0; t < 64; ++t) {
        const unsigned short* tA = &lds[t & 1][0][0];
        const unsigned short* tB = &lds[t & 1][1][0];
        #pragma unroll
        for (int p = 0; p < 4; ++p) {
            const int ks = p >> 1, mh = p & 1;   // phases: (k0,m0)(k0,m1)(k1,m0)(k1,m1)
            if (mh == 0) {
                #pragma unroll
                for (int nf = 0; nf < 4; ++nf) {
                    int byte = ks * 16384 + (wn * 4 + nf) * 1024 + (l & 15) * 64 + ((l >> 4) << 4);
                    byte ^= (l & 8) << 2;
                    bfr[nf] = *(const short8*)((const char*)tB + byte);
                }
            }
            #pragma unroll
            for (int i = 0; i < 4; ++i) {
                int byte = ks * 16384 + (wm * 8 + mh * 4 + i) * 1024 + (l & 15) * 64 + ((l >> 4) << 4);
                byte ^= (l & 8) << 2;
                afr[i] = *(const short8*)((const char*)tA + byte);
            }
            // stage stream 4t+p+6: p0/p1 -> tile t+1 k1-halves (other buffer, safe);
            // p2/p3 -> tile t+2 k0-halves (this buffer, k0 fully consumed after p1 barrier)
            int s = 4 * t + p + 6;
            if (s < 256) stage(s);
            __builtin_amdgcn_s_barrier();
            asm volatile("s_waitcnt lgkmcnt(0)" ::: "memory");
            __builtin_amdgcn_s_setprio(1);
            #pragma unroll
            for (int i = 0; i < 4; ++i)
                #pragma unroll
                for (int nf = 0; nf < 4; ++nf)
                    acc[mh * 4 + i][nf] = __builtin_amdgcn_mfma_f32_16x16x32_bf16(
                        afr[i], bfr[nf], acc[mh * 4 + i][nf], 0, 0, 0);
            __builtin_amdgcn_s_setprio(0);
            if (p == 3) {
                // counted drain: tile t+1 fully landed; <=2 half-tiles (4 loads) in flight
                if (t < 62) asm volatile("s_waitcnt vmcnt(4)" ::: "memory");
                else        asm volatile("s_waitcnt vmcnt(0)" ::: "memory");
            }
            __builtin_amdgcn_s_barrier();
        }
    }

    // epilogue: C/D layout col=lane&15, row=(lane>>4)*4+j
    const int crow = (l >> 4) * 4, ccol = l & 15;
    #pragma unroll
    for (int nf = 0; nf < 4; ++nf) {
        int col = bn0 + wn * 64 + nf * 16 + ccol;
        float bv = bias[col];
        #pragma unroll
        for (int m = 0; m < 8; ++m) {
            int row0 = bm0 + wm * 128 + m * 16 + crow;
            #pragma unroll
            for (int j2 = 0; j2 < 4; ++j2)
                out[(size_t)(row0 + j2) * NDIM + col] = acc[m][nf][j2] + bv;
        }
    }
}

// ---------------- fallback: fused dequant GEMM (if ws too small) ----------------
__global__ __launch_bounds__(256, 2) void gemm_fused(const float* __restrict__ x,
                                                     const int* __restrict__ wp,
                                                     const int* __restrict__ wse,
                                                     const float* __restrict__ bias,
                                                     float* __restrict__ out) {
    __shared__ __attribute__((aligned(16))) unsigned short lA[128 * 64];
    __shared__ __attribute__((aligned(16))) unsigned short lB[128 * 64];
    const int tid = threadIdx.x;
    const int l = tid & 63, wid = tid >> 6;
    const int bn0 = blockIdx.x * 128, bm0 = blockIdx.y * 128;
    const int wm = wid >> 1, wn = wid & 1;

    f32x4 acc[4][4] = {};

    for (int k0 = 0; k0 < KDIM; k0 += 64) {
        float4 av0[4], av1[4];
        unsigned int bp[4];
        int be[4];
        #pragma unroll
        for (int i = 0; i < 4; ++i) {
            int seg = i * 256 + tid;
            int row = seg >> 3, kseg = seg & 7;
            const float4* p = (const float4*)(x + (size_t)(bm0 + row) * KDIM + k0 + kseg * 8);
            av0[i] = p[0]; av1[i] = p[1];
        }
        #pragma unroll
        for (int i = 0; i < 4; ++i) {
            int idx = i * 256 + tid;
            int ln = idx & 127, lr = idx >> 7;
            bp[i] = ((const unsigned int*)wp)[(size_t)(k0 / 8 + lr) * NDIM + bn0 + ln];
            be[i] = wse[(size_t)((k0 + lr * 8) >> 5) * NDIM + bn0 + ln];
        }
        #pragma unroll
        for (int i = 0; i < 4; ++i) {
            int seg = i * 256 + tid;
            int row = seg >> 3, kseg = seg & 7;
            ushort8 r;
            r[0] = f2bf(av0[i].x); r[1] = f2bf(av0[i].y); r[2] = f2bf(av0[i].z); r[3] = f2bf(av0[i].w);
            r[4] = f2bf(av1[i].x); r[5] = f2bf(av1[i].y); r[6] = f2bf(av1[i].z); r[7] = f2bf(av1[i].w);
            *(ushort8*)&lA[row * 64 + kseg * 8] = r;
        }
        #pragma unroll
        for (int i = 0; i < 4; ++i) {
            int idx = i * 256 + tid;
            int ln = idx & 127, lr = idx >> 7;
            unsigned int p = bp[i];
            int e = be[i];
            ushort8 r;
            #pragma unroll
            for (int j = 0; j < 8; ++j) r[j] = nib2bf((p >> (4 * j)) & 0xFu, e);
            *(ushort8*)&lB[ln * 64 + lr * 8] = r;
        }
        __syncthreads();
        #pragma unroll
        for (int kc = 0; kc < 2; ++kc) {
            short8 a[4], b[4];
            #pragma unroll
            for (int f = 0; f < 4; ++f) {
                a[f] = *(const short8*)&lA[(wm * 64 + f * 16 + (l & 15)) * 64 + kc * 32 + (l >> 4) * 8];
                b[f] = *(const short8*)&lB[(wn * 64 + f * 16 + (l & 15)) * 64 + kc * 32 + (l >> 4) * 8];
            }
            #pragma unroll
            for (int fm = 0; fm < 4; ++fm)
                #pragma unroll
                for (int fn = 0; fn < 4; ++fn)
                    acc[fm][fn] = __builtin_amdgcn_mfma_f32_16x16x32_bf16(a[fm], b[fn], acc[fm][fn], 0, 0, 0);
        }
        __syncthreads();
    }

    const int crow = (l >> 4) * 4, ccol = l & 15;
    #pragma unroll
    for (int fn = 0; fn < 4; ++fn) {
        int col = bn0 + wn * 64 + fn * 16 + ccol;
        float bv = bias[col];
        #pragma unroll
        for (int fm = 0; fm < 4; ++fm) {
            int row0 = bm0 + wm * 64 + fm * 16 + crow;
            #pragma unroll
            for (int j = 0; j < 4; ++j)
                out[(size_t)(row0 + j) * NDIM + col] = acc[fm][fn][j] + bv;
        }
    }
}

extern "C" void kernel_launch(void* const* d_in, const int* in_sizes, int n_in,
                              void* d_out, int out_size, void* d_ws, size_t ws_size,
                              hipStream_t stream) {
    (void)in_sizes; (void)n_in; (void)out_size;
    const float* x = (const float*)d_in[0];
    const int* wp = (const int*)d_in[1];
    const int* wse = (const int*)d_in[2];
    const float* bias = (const float*)d_in[3];
    float* out = (float*)d_out;

    const size_t xbf_bytes = (size_t)TDIM * KDIM * 2;  // 67.1 MB
    const size_t wt_bytes = (size_t)NDIM * KDIM * 2;   // 90.2 MB

    if (ws_size >= xbf_bytes + wt_bytes) {
        unsigned short* xbf = (unsigned short*)d_ws;
        unsigned short* wt = (unsigned short*)((char*)d_ws + xbf_bytes);
        hipLaunchKernelGGL(convert_x, dim3((TDIM * KDIM) / (256 * 8)), dim3(256), 0, stream, x, xbf);
        hipLaunchKernelGGL(dequant_w, dim3(NDIM / 64, (KDIM / 8) / 64), dim3(256), 0, stream, wp, wse, wt);
        hipLaunchKernelGGL(gemm256, dim3((NDIM / 256) * (TDIM / 256)), dim3(512), 0, stream, xbf, wt, bias, out);
    } else {
        hipLaunchKernelGGL(gemm_fused, dim3(NDIM / 128, TDIM / 128), dim3(256), 0, stream, x, wp, wse, bias, out);
    }
}

// Round 3
// 737.611 us; speedup vs baseline: 1.4264x; 1.1018x over previous
//
#include <hip/hip_runtime.h>

// QuantLinear: out[T,N] = x[T,K] @ dequant(W)[K,N] + bias
// T=8192, K=4096, N=11008. Pre-pass: x->bf16, W->bf16 W^T [N][K] in d_ws.
// Main GEMM: 256x256 tile, BK=64, 8 waves (2Mx4N), 8-phase schedule with
// st_16x32 LDS swizzle, counted vmcnt, setprio, and XCD supertile mapping:
// each XCD's 32 concurrent blocks cover an 8(bm)x4(bn) supertile so A/B
// panel re-reads hit that XCD's L2 instead of streaming from L3/HBM.

#define TDIM 8192
#define KDIM 4096
#define NDIM 11008

typedef __attribute__((ext_vector_type(8))) short short8;
typedef __attribute__((ext_vector_type(8))) unsigned short ushort8;
typedef __attribute__((ext_vector_type(4))) float f32x4;

__device__ __forceinline__ unsigned short f2bf(float f) {
    unsigned int u = __float_as_uint(f);
    u += 0x7FFFu + ((u >> 16) & 1u);   // round-to-nearest-even
    return (unsigned short)(u >> 16);
}

// fp4 e2m1 nibble + e8m0 exponent -> exact bf16 bits.
__device__ __forceinline__ unsigned short nib2bf(unsigned int v, int e) {
    unsigned int m3 = v & 7u;
    if (m3 == 0u) return 0;
    unsigned int s = (v & 8u) << 12;
    unsigned int E = (unsigned int)e + (m3 >> 1) - 1u;
    unsigned int man = (m3 >= 2u) ? ((m3 & 1u) << 6) : 0u;
    return (unsigned short)(s | (E << 7) | man);
}

__device__ __forceinline__ void gload_lds16(const void* g, void* l) {
    __builtin_amdgcn_global_load_lds(
        (const __attribute__((address_space(1))) void*)g,
        (__attribute__((address_space(3))) void*)l, 16, 0, 0);
}

// ---------------- pre-pass 1: x fp32 -> bf16 ----------------
__global__ __launch_bounds__(256) void convert_x(const float* __restrict__ x,
                                                 unsigned short* __restrict__ xbf) {
    size_t i = ((size_t)blockIdx.x * 256 + threadIdx.x) * 8;
    float4 v0 = *(const float4*)(x + i);
    float4 v1 = *(const float4*)(x + i + 4);
    ushort8 r;
    r[0] = f2bf(v0.x); r[1] = f2bf(v0.y); r[2] = f2bf(v0.z); r[3] = f2bf(v0.w);
    r[4] = f2bf(v1.x); r[5] = f2bf(v1.y); r[6] = f2bf(v1.z); r[7] = f2bf(v1.w);
    *(ushort8*)(xbf + i) = r;
}

// ---------------- pre-pass 2: dequant W -> W^T bf16 [N][K] ----------------
__global__ __launch_bounds__(256) void dequant_w(const int* __restrict__ wp,
                                                 const int* __restrict__ wse,
                                                 unsigned short* __restrict__ wt) {
    __shared__ int sT[64][65];
    const int tid = threadIdx.x;
    const int n0 = blockIdx.x * 64;
    const int r0 = blockIdx.y * 64;

    #pragma unroll
    for (int i = 0; i < 16; ++i) {
        int idx = i * 256 + tid;
        int r = idx >> 6, n = idx & 63;
        sT[r][n] = wp[(size_t)(r0 + r) * NDIM + n0 + n];
    }
    __syncthreads();
    #pragma unroll
    for (int i = 0; i < 16; ++i) {
        int idx = i * 256 + tid;
        int n = idx >> 6, r = idx & 63;
        unsigned int p = (unsigned int)sT[r][n];
        int e = wse[(size_t)((r0 + r) >> 2) * NDIM + n0 + n];
        ushort8 o;
        #pragma unroll
        for (int j = 0; j < 8; ++j) o[j] = nib2bf((p >> (4 * j)) & 0xFu, e);
        *(ushort8*)(wt + (size_t)(n0 + n) * KDIM + (size_t)(r0 + r) * 8) = o;
    }
}

// ---------------- main GEMM: 256x256 tile, BK=64, 8 waves, 8-phase ----------------
__global__ __launch_bounds__(512, 1) void gemm256(const unsigned short* __restrict__ xbf,
                                                  const unsigned short* __restrict__ wt,
                                                  const float* __restrict__ bias,
                                                  float* __restrict__ out) {
    __shared__ __attribute__((aligned(16))) unsigned short lds[2][2][16384]; // 128 KiB
    const int tid = threadIdx.x;
    const int l = tid & 63, wid = tid >> 6;
    const int wm = wid >> 2, wn = wid & 3;   // 2 x 4 waves; per-wave 128 rows x 64 cols

    // --- XCD supertile mapping ---
    // b%8 -> XCD; XCD x runs swz = x*172 + b/8 in order. Decode swz into an
    // 8(bm)x4(bn) supertile of 32 blocks so the XCD's concurrent generation
    // shares 8 A-panels + 4 B-panels in its L2. Grid: 4 bm-bands of 8 rows;
    // per band 10 full supertiles (4-wide) + 1 ragged (3-wide), 43 bn total.
    {
    }
    int b = blockIdx.x;
    int swz = (b & 7) * 172 + (b >> 3);        // bijective: 1376 = 8*172
    int band = swz / 344;                       // bm-band of 8 rows (344 = 8*43)
    int r = swz % 344;
    int st = r >> 5; if (st > 10) st = 10;      // supertile within band
    int ii = r - (st << 5);                     // index within supertile
    int w = (st < 10) ? 4 : 3;                  // supertile bn-width
    const int bm0 = (band * 8 + ii / w) * 256;
    const int bn0 = (st * 4 + ii % w) * 256;

    // per-thread staging decode for linear-dest chunk -> (row, k-offset) inverse swizzle
    int r_s[2], k_s[2];
    #pragma unroll
    for (int j = 0; j < 2; ++j) {
        int chunk = j * 512 + wid * 64 + l;   // 16B chunk index within 16KB half-tile
        int sr = chunk >> 6;
        int cin = chunk & 63;
        cin ^= ((cin >> 5) & 1) << 1;         // inverse of byte-bit5^=bit9 (16B units)
        r_s[j] = sr * 16 + (cin >> 2);
        k_s[j] = (cin & 3) * 8;
    }

    f32x4 acc[8][4] = {};
    short8 afr[4], bfr[4];

    // stage one half-tile: stream s -> tile s>>2, idx s&3: 0=A.k0 1=B.k0 2=A.k1 3=B.k1
    auto stage = [&](int s) {
        int tau = s >> 2;
        int idx = s & 3;
        int mat = idx & 1, hk = idx >> 1, c = tau & 1;
        const unsigned short* base = mat ? wt : xbf;
        int rb = mat ? bn0 : bm0;
        int kb = tau * 64 + hk * 32;
        #pragma unroll
        for (int j = 0; j < 2; ++j) {
            const unsigned short* src = base + (size_t)(rb + r_s[j]) * KDIM + kb + k_s[j];
            unsigned short* dst = &lds[c][mat][hk * 8192 + (j * 512 + wid * 64) * 8];
            gload_lds16(src, dst);
        }
    };

    // prologue: tile 0 (4 half-tiles) + tile 1's k0 halves
    #pragma unroll
    for (int s = 0; s < 6; ++s) stage(s);
    asm volatile("s_waitcnt vmcnt(4)" ::: "memory");   // tile 0 landed
    __builtin_amdgcn_s_barrier();

    #pragma unroll 2
    for (int t = 0; t < 64; ++t) {
        const unsigned short* tA = &lds[t & 1][0][0];
        const unsigned short* tB = &lds[t & 1][1][0];
        #pragma unroll
        for (int p = 0; p < 4; ++p) {
            const int ks = p >> 1, mh = p & 1;   // phases: (k0,m0)(k0,m1)(k1,m0)(k1,m1)
            if (mh == 0) {
                #pragma unroll
                for (int nf = 0; nf < 4; ++nf) {
                    int byte = ks * 16384 + (wn * 4 + nf) * 1024 + (l & 15) * 64 + ((l >> 4) << 4);
                    byte ^= (l & 8) << 2;
                    bfr[nf] = *(const short8*)((const char*)tB + byte);
                }
            }
            #pragma unroll
            for (int i = 0; i < 4; ++i) {
                int byte = ks * 16384 + (wm * 8 + mh * 4 + i) * 1024 + (l & 15) * 64 + ((l >> 4) << 4);
                byte ^= (l & 8) << 2;
                afr[i] = *(const short8*)((const char*)tA + byte);
            }
            // stage stream 4t+p+6: p0/p1 -> tile t+1 k1-halves (other buffer, safe);
            // p2/p3 -> tile t+2 k0-halves (this buffer, k0 fully consumed after p1 barrier)
            int s = 4 * t + p + 6;
            if (s < 256) stage(s);
            __builtin_amdgcn_s_barrier();
            asm volatile("s_waitcnt lgkmcnt(0)" ::: "memory");
            __builtin_amdgcn_s_setprio(1);
            #pragma unroll
            for (int i = 0; i < 4; ++i)
                #pragma unroll
                for (int nf = 0; nf < 4; ++nf)
                    acc[mh * 4 + i][nf] = __builtin_amdgcn_mfma_f32_16x16x32_bf16(
                        afr[i], bfr[nf], acc[mh * 4 + i][nf], 0, 0, 0);
            __builtin_amdgcn_s_setprio(0);
            if (p == 3) {
                // counted drain: tile t+1 fully landed; <=1 half-tile pair in flight
                if (t < 62) asm volatile("s_waitcnt vmcnt(4)" ::: "memory");
                else        asm volatile("s_waitcnt vmcnt(0)" ::: "memory");
            }
            __builtin_amdgcn_s_barrier();
        }
    }

    // epilogue: C/D layout col=lane&15, row=(lane>>4)*4+j; nontemporal stores
    // (360 MB output stream must not evict L3-resident x/W panels)
    const int crow = (l >> 4) * 4, ccol = l & 15;
    #pragma unroll
    for (int nf = 0; nf < 4; ++nf) {
        int col = bn0 + wn * 64 + nf * 16 + ccol;
        float bv = bias[col];
        #pragma unroll
        for (int m = 0; m < 8; ++m) {
            int row0 = bm0 + wm * 128 + m * 16 + crow;
            #pragma unroll
            for (int j2 = 0; j2 < 4; ++j2)
                __builtin_nontemporal_store(acc[m][nf][j2] + bv,
                                            &out[(size_t)(row0 + j2) * NDIM + col]);
        }
    }
}

// ---------------- fallback: fused dequant GEMM (if ws too small) ----------------
__global__ __launch_bounds__(256, 2) void gemm_fused(const float* __restrict__ x,
                                                     const int* __restrict__ wp,
                                                     const int* __restrict__ wse,
                                                     const float* __restrict__ bias,
                                                     float* __restrict__ out) {
    __shared__ __attribute__((aligned(16))) unsigned short lA[128 * 64];
    __shared__ __attribute__((aligned(16))) unsigned short lB[128 * 64];
    const int tid = threadIdx.x;
    const int l = tid & 63, wid = tid >> 6;
    const int bn0 = blockIdx.x * 128, bm0 = blockIdx.y * 128;
    const int wm = wid >> 1, wn = wid & 1;

    f32x4 acc[4][4] = {};

    for (int k0 = 0; k0 < KDIM; k0 += 64) {
        float4 av0[4], av1[4];
        unsigned int bp[4];
        int be[4];
        #pragma unroll
        for (int i = 0; i < 4; ++i) {
            int seg = i * 256 + tid;
            int row = seg >> 3, kseg = seg & 7;
            const float4* p = (const float4*)(x + (size_t)(bm0 + row) * KDIM + k0 + kseg * 8);
            av0[i] = p[0]; av1[i] = p[1];
        }
        #pragma unroll
        for (int i = 0; i < 4; ++i) {
            int idx = i * 256 + tid;
            int ln = idx & 127, lr = idx >> 7;
            bp[i] = ((const unsigned int*)wp)[(size_t)(k0 / 8 + lr) * NDIM + bn0 + ln];
            be[i] = wse[(size_t)((k0 + lr * 8) >> 5) * NDIM + bn0 + ln];
        }
        #pragma unroll
        for (int i = 0; i < 4; ++i) {
            int seg = i * 256 + tid;
            int row = seg >> 3, kseg = seg & 7;
            ushort8 r;
            r[0] = f2bf(av0[i].x); r[1] = f2bf(av0[i].y); r[2] = f2bf(av0[i].z); r[3] = f2bf(av0[i].w);
            r[4] = f2bf(av1[i].x); r[5] = f2bf(av1[i].y); r[6] = f2bf(av1[i].z); r[7] = f2bf(av1[i].w);
            *(ushort8*)&lA[row * 64 + kseg * 8] = r;
        }
        #pragma unroll
        for (int i = 0; i < 4; ++i) {
            int idx = i * 256 + tid;
            int ln = idx & 127, lr = idx >> 7;
            unsigned int p = bp[i];
            int e = be[i];
            ushort8 r;
            #pragma unroll
            for (int j = 0; j < 8; ++j) r[j] = nib2bf((p >> (4 * j)) & 0xFu, e);
            *(ushort8*)&lB[ln * 64 + lr * 8] = r;
        }
        __syncthreads();
        #pragma unroll
        for (int kc = 0; kc < 2; ++kc) {
            short8 a[4], b[4];
            #pragma unroll
            for (int f = 0; f < 4; ++f) {
                a[f] = *(const short8*)&lA[(wm * 64 + f * 16 + (l & 15)) * 64 + kc * 32 + (l >> 4) * 8];
                b[f] = *(const short8*)&lB[(wn * 64 + f * 16 + (l & 15)) * 64 + kc * 32 + (l >> 4) * 8];
            }
            #pragma unroll
            for (int fm = 0; fm < 4; ++fm)
                #pragma unroll
                for (int fn = 0; fn < 4; ++fn)
                    acc[fm][fn] = __builtin_amdgcn_mfma_f32_16x16x32_bf16(a[fm], b[fn], acc[fm][fn], 0, 0, 0);
        }
        __syncthreads();
    }

    const int crow = (l >> 4) * 4, ccol = l & 15;
    #pragma unroll
    for (int fn = 0; fn < 4; ++fn) {
        int col = bn0 + wn * 64 + fn * 16 + ccol;
        float bv = bias[col];
        #pragma unroll
        for (int fm = 0; fm < 4; ++fm) {
            int row0 = bm0 + wm * 64 + fm * 16 + crow;
            #pragma unroll
            for (int j = 0; j < 4; ++j)
                out[(size_t)(row0 + j) * NDIM + col] = acc[fm][fn][j] + bv;
        }
    }
}

extern "C" void kernel_launch(void* const* d_in, const int* in_sizes, int n_in,
                              void* d_out, int out_size, void* d_ws, size_t ws_size,
                              hipStream_t stream) {
    (void)in_sizes; (void)n_in; (void)out_size;
    const float* x = (const float*)d_in[0];
    const int* wp = (const int*)d_in[1];
    const int* wse = (const int*)d_in[2];
    const float* bias = (const float*)d_in[3];
    float* out = (float*)d_out;

    const size_t xbf_bytes = (size_t)TDIM * KDIM * 2;  // 67.1 MB
    const size_t wt_bytes = (size_t)NDIM * KDIM * 2;   // 90.2 MB

    if (ws_size >= xbf_bytes + wt_bytes) {
        unsigned short* xbf = (unsigned short*)d_ws;
        unsigned short* wt = (unsigned short*)((char*)d_ws + xbf_bytes);
        hipLaunchKernelGGL(convert_x, dim3((TDIM * KDIM) / (256 * 8)), dim3(256), 0, stream, x, xbf);
        hipLaunchKernelGGL(dequant_w, dim3(NDIM / 64, (KDIM / 8) / 64), dim3(256), 0, stream, wp, wse, wt);
        hipLaunchKernelGGL(gemm256, dim3((NDIM / 256) * (TDIM / 256)), dim3(512), 0, stream, xbf, wt, bias, out);
    } else {
        hipLaunchKernelGGL(gemm_fused, dim3(NDIM / 128, TDIM / 128), dim3(256), 0, stream, x, wp, wse, bias, out);
    }
}

// Round 4
// 720.400 us; speedup vs baseline: 1.4605x; 1.0239x over previous
//
#include <hip/hip_runtime.h>

// QuantLinear: out[T,N] = x[T,K] @ dequant(W)[K,N] + bias
// T=8192, K=4096, N=11008. Pre-pass: x->bf16, W->bf16 W^T [N][K] in d_ws.
// Main GEMM: 256x256 tile, BK=64, 8 waves (2Mx4N), 4-phase/K-tile schedule,
// st_16x32 LDS swizzle, ONE barrier per phase (waves free-run within a phase
// so ds_read/VALU segments overlap other waves' MFMA clusters), deep split
// vmcnt(8) waits (every wait targets loads >=4 phases old), setprio around
// MFMA, XCD supertile mapping for L2 panel sharing.

#define TDIM 8192
#define KDIM 4096
#define NDIM 11008

typedef __attribute__((ext_vector_type(8))) short short8;
typedef __attribute__((ext_vector_type(8))) unsigned short ushort8;
typedef __attribute__((ext_vector_type(4))) float f32x4;

__device__ __forceinline__ unsigned short f2bf(float f) {
    unsigned int u = __float_as_uint(f);
    u += 0x7FFFu + ((u >> 16) & 1u);   // round-to-nearest-even
    return (unsigned short)(u >> 16);
}

// fp4 e2m1 nibble + e8m0 exponent -> exact bf16 bits.
__device__ __forceinline__ unsigned short nib2bf(unsigned int v, int e) {
    unsigned int m3 = v & 7u;
    if (m3 == 0u) return 0;
    unsigned int s = (v & 8u) << 12;
    unsigned int E = (unsigned int)e + (m3 >> 1) - 1u;
    unsigned int man = (m3 >= 2u) ? ((m3 & 1u) << 6) : 0u;
    return (unsigned short)(s | (E << 7) | man);
}

__device__ __forceinline__ void gload_lds16(const void* g, void* l) {
    __builtin_amdgcn_global_load_lds(
        (const __attribute__((address_space(1))) void*)g,
        (__attribute__((address_space(3))) void*)l, 16, 0, 0);
}

// ---------------- pre-pass 1: x fp32 -> bf16 ----------------
__global__ __launch_bounds__(256) void convert_x(const float* __restrict__ x,
                                                 unsigned short* __restrict__ xbf) {
    size_t i = ((size_t)blockIdx.x * 256 + threadIdx.x) * 8;
    float4 v0 = *(const float4*)(x + i);
    float4 v1 = *(const float4*)(x + i + 4);
    ushort8 r;
    r[0] = f2bf(v0.x); r[1] = f2bf(v0.y); r[2] = f2bf(v0.z); r[3] = f2bf(v0.w);
    r[4] = f2bf(v1.x); r[5] = f2bf(v1.y); r[6] = f2bf(v1.z); r[7] = f2bf(v1.w);
    *(ushort8*)(xbf + i) = r;
}

// ---------------- pre-pass 2: dequant W -> W^T bf16 [N][K] ----------------
__global__ __launch_bounds__(256) void dequant_w(const int* __restrict__ wp,
                                                 const int* __restrict__ wse,
                                                 unsigned short* __restrict__ wt) {
    __shared__ int sT[64][65];
    const int tid = threadIdx.x;
    const int n0 = blockIdx.x * 64;
    const int r0 = blockIdx.y * 64;

    #pragma unroll
    for (int i = 0; i < 16; ++i) {
        int idx = i * 256 + tid;
        int r = idx >> 6, n = idx & 63;
        sT[r][n] = wp[(size_t)(r0 + r) * NDIM + n0 + n];
    }
    __syncthreads();
    #pragma unroll
    for (int i = 0; i < 16; ++i) {
        int idx = i * 256 + tid;
        int n = idx >> 6, r = idx & 63;
        unsigned int p = (unsigned int)sT[r][n];
        int e = wse[(size_t)((r0 + r) >> 2) * NDIM + n0 + n];
        ushort8 o;
        #pragma unroll
        for (int j = 0; j < 8; ++j) o[j] = nib2bf((p >> (4 * j)) & 0xFu, e);
        *(ushort8*)(wt + (size_t)(n0 + n) * KDIM + (size_t)(r0 + r) * 8) = o;
    }
}

// ---------------- main GEMM: 256x256 tile, BK=64, 8 waves ----------------
__global__ __launch_bounds__(512, 1) void gemm256(const unsigned short* __restrict__ xbf,
                                                  const unsigned short* __restrict__ wt,
                                                  const float* __restrict__ bias,
                                                  float* __restrict__ out) {
    __shared__ __attribute__((aligned(16))) unsigned short lds[2][2][16384]; // 128 KiB
    const int tid = threadIdx.x;
    const int l = tid & 63, wid = tid >> 6;
    const int wm = wid >> 2, wn = wid & 3;   // 2 x 4 waves; per-wave 128 rows x 64 cols

    // --- XCD supertile mapping ---
    // b%8 -> XCD; XCD x runs swz = x*172 + b/8 in order. Decode swz into an
    // 8(bm)x4(bn) supertile of 32 blocks so the XCD's concurrent generation
    // shares 8 A-panels + 4 B-panels in its L2.
    int b = blockIdx.x;
    int swz = (b & 7) * 172 + (b >> 3);        // bijective: 1376 = 8*172
    int band = swz / 344;                       // bm-band of 8 rows (344 = 8*43)
    int r = swz % 344;
    int st = r >> 5; if (st > 10) st = 10;      // supertile within band
    int ii = r - (st << 5);                     // index within supertile
    int w = (st < 10) ? 4 : 3;                  // supertile bn-width
    const int bm0 = (band * 8 + ii / w) * 256;
    const int bn0 = (st * 4 + ii % w) * 256;

    // per-thread staging decode for linear-dest chunk -> (row, k-offset) inverse swizzle
    int r_s[2], k_s[2];
    #pragma unroll
    for (int j = 0; j < 2; ++j) {
        int chunk = j * 512 + wid * 64 + l;   // 16B chunk index within 16KB half-tile
        int sr = chunk >> 6;
        int cin = chunk & 63;
        cin ^= ((cin >> 5) & 1) << 1;         // inverse of byte-bit5^=bit9 (16B units)
        r_s[j] = sr * 16 + (cin >> 2);
        k_s[j] = (cin & 3) * 8;
    }

    f32x4 acc[8][4] = {};
    short8 afr[4], bfr[4];

    // stage one half-tile: stream s -> tile s>>2, idx s&3: 0=A.k0 1=B.k0 2=A.k1 3=B.k1
    auto stage = [&](int s) {
        int tau = s >> 2;
        int idx = s & 3;
        int mat = idx & 1, hk = idx >> 1, c = tau & 1;
        const unsigned short* base = mat ? wt : xbf;
        int rb = mat ? bn0 : bm0;
        int kb = tau * 64 + hk * 32;
        #pragma unroll
        for (int j = 0; j < 2; ++j) {
            const unsigned short* src = base + (size_t)(rb + r_s[j]) * KDIM + kb + k_s[j];
            unsigned short* dst = &lds[c][mat][hk * 8192 + (j * 512 + wid * 64) * 8];
            gload_lds16(src, dst);
        }
    };

    // prologue: tile 0 (4 half-tiles) + tile 1's k0 halves
    #pragma unroll
    for (int s = 0; s < 6; ++s) stage(s);
    asm volatile("s_waitcnt vmcnt(4)" ::: "memory");   // tile 0 landed
    __builtin_amdgcn_s_barrier();

    #pragma unroll 2
    for (int t = 0; t < 64; ++t) {
        const unsigned short* tA = &lds[t & 1][0][0];
        const unsigned short* tB = &lds[t & 1][1][0];
        #pragma unroll
        for (int p = 0; p < 4; ++p) {
            const int ks = p >> 1, mh = p & 1;   // phases: (k0,m0)(k0,m1)(k1,m0)(k1,m1)
            if (mh == 0) {
                #pragma unroll
                for (int nf = 0; nf < 4; ++nf) {
                    int byte = ks * 16384 + (wn * 4 + nf) * 1024 + (l & 15) * 64 + ((l >> 4) << 4);
                    byte ^= (l & 8) << 2;
                    bfr[nf] = *(const short8*)((const char*)tB + byte);
                }
            }
            #pragma unroll
            for (int i = 0; i < 4; ++i) {
                int byte = ks * 16384 + (wm * 8 + mh * 4 + i) * 1024 + (l & 15) * 64 + ((l >> 4) << 4);
                byte ^= (l & 8) << 2;
                afr[i] = *(const short8*)((const char*)tA + byte);
            }
            // stage stream 4t+p+6: p0/p1 -> tile t+1 k1-halves (other buffer, safe);
            // p2/p3 -> tile t+2 k0-halves (this buffer, k0 consumed after p1's end-barrier)
            int s = 4 * t + p + 6;
            if (s < 256) stage(s);
            // no mid-barrier: waves free-run; frag deps enforced by compiler waitcnt,
            // cross-wave staging safety by per-wave vmcnt + the single end-barrier.
            __builtin_amdgcn_s_setprio(1);
            #pragma unroll
            for (int i = 0; i < 4; ++i)
                #pragma unroll
                for (int nf = 0; nf < 4; ++nf)
                    acc[mh * 4 + i][nf] = __builtin_amdgcn_mfma_f32_16x16x32_bf16(
                        afr[i], bfr[nf], acc[mh * 4 + i][nf], 0, 0, 0);
            __builtin_amdgcn_s_setprio(0);
            // deep split waits: every wait targets loads issued >=4 phases earlier
            if (p == 1) {
                // this tile's k1 halves (issued at prev tile p0/p1) must be landed
                if (t < 63) asm volatile("s_waitcnt vmcnt(8)" ::: "memory");
                else        asm volatile("s_waitcnt vmcnt(0)" ::: "memory");
            } else if (p == 3) {
                // next tile's k0 halves (issued at this tile p2/p3... no, at t-1 p2/p3
                // relative ordering: ensures streams through 4t+5 landed)
                if (t < 62)       asm volatile("s_waitcnt vmcnt(8)" ::: "memory");
                else if (t == 62) asm volatile("s_waitcnt vmcnt(4)" ::: "memory");
            }
            __builtin_amdgcn_s_barrier();
        }
    }

    // epilogue: C/D layout col=lane&15, row=(lane>>4)*4+j; nontemporal stores
    const int crow = (l >> 4) * 4, ccol = l & 15;
    #pragma unroll
    for (int nf = 0; nf < 4; ++nf) {
        int col = bn0 + wn * 64 + nf * 16 + ccol;
        float bv = bias[col];
        #pragma unroll
        for (int m = 0; m < 8; ++m) {
            int row0 = bm0 + wm * 128 + m * 16 + crow;
            #pragma unroll
            for (int j2 = 0; j2 < 4; ++j2)
                __builtin_nontemporal_store(acc[m][nf][j2] + bv,
                                            &out[(size_t)(row0 + j2) * NDIM + col]);
        }
    }
}

// ---------------- fallback: fused dequant GEMM (if ws too small) ----------------
__global__ __launch_bounds__(256, 2) void gemm_fused(const float* __restrict__ x,
                                                     const int* __restrict__ wp,
                                                     const int* __restrict__ wse,
                                                     const float* __restrict__ bias,
                                                     float* __restrict__ out) {
    __shared__ __attribute__((aligned(16))) unsigned short lA[128 * 64];
    __shared__ __attribute__((aligned(16))) unsigned short lB[128 * 64];
    const int tid = threadIdx.x;
    const int l = tid & 63, wid = tid >> 6;
    const int bn0 = blockIdx.x * 128, bm0 = blockIdx.y * 128;
    const int wm = wid >> 1, wn = wid & 1;

    f32x4 acc[4][4] = {};

    for (int k0 = 0; k0 < KDIM; k0 += 64) {
        float4 av0[4], av1[4];
        unsigned int bp[4];
        int be[4];
        #pragma unroll
        for (int i = 0; i < 4; ++i) {
            int seg = i * 256 + tid;
            int row = seg >> 3, kseg = seg & 7;
            const float4* p = (const float4*)(x + (size_t)(bm0 + row) * KDIM + k0 + kseg * 8);
            av0[i] = p[0]; av1[i] = p[1];
        }
        #pragma unroll
        for (int i = 0; i < 4; ++i) {
            int idx = i * 256 + tid;
            int ln = idx & 127, lr = idx >> 7;
            bp[i] = ((const unsigned int*)wp)[(size_t)(k0 / 8 + lr) * NDIM + bn0 + ln];
            be[i] = wse[(size_t)((k0 + lr * 8) >> 5) * NDIM + bn0 + ln];
        }
        #pragma unroll
        for (int i = 0; i < 4; ++i) {
            int seg = i * 256 + tid;
            int row = seg >> 3, kseg = seg & 7;
            ushort8 r;
            r[0] = f2bf(av0[i].x); r[1] = f2bf(av0[i].y); r[2] = f2bf(av0[i].z); r[3] = f2bf(av0[i].w);
            r[4] = f2bf(av1[i].x); r[5] = f2bf(av1[i].y); r[6] = f2bf(av1[i].z); r[7] = f2bf(av1[i].w);
            *(ushort8*)&lA[row * 64 + kseg * 8] = r;
        }
        #pragma unroll
        for (int i = 0; i < 4; ++i) {
            int idx = i * 256 + tid;
            int ln = idx & 127, lr = idx >> 7;
            unsigned int p = bp[i];
            int e = be[i];
            ushort8 r;
            #pragma unroll
            for (int j = 0; j < 8; ++j) r[j] = nib2bf((p >> (4 * j)) & 0xFu, e);
            *(ushort8*)&lB[ln * 64 + lr * 8] = r;
        }
        __syncthreads();
        #pragma unroll
        for (int kc = 0; kc < 2; ++kc) {
            short8 a[4], b[4];
            #pragma unroll
            for (int f = 0; f < 4; ++f) {
                a[f] = *(const short8*)&lA[(wm * 64 + f * 16 + (l & 15)) * 64 + kc * 32 + (l >> 4) * 8];
                b[f] = *(const short8*)&lB[(wn * 64 + f * 16 + (l & 15)) * 64 + kc * 32 + (l >> 4) * 8];
            }
            #pragma unroll
            for (int fm = 0; fm < 4; ++fm)
                #pragma unroll
                for (int fn = 0; fn < 4; ++fn)
                    acc[fm][fn] = __builtin_amdgcn_mfma_f32_16x16x32_bf16(a[fm], b[fn], acc[fm][fn], 0, 0, 0);
        }
        __syncthreads();
    }

    const int crow = (l >> 4) * 4, ccol = l & 15;
    #pragma unroll
    for (int fn = 0; fn < 4; ++fn) {
        int col = bn0 + wn * 64 + fn * 16 + ccol;
        float bv = bias[col];
        #pragma unroll
        for (int fm = 0; fm < 4; ++fm) {
            int row0 = bm0 + wm * 64 + fm * 16 + crow;
            #pragma unroll
            for (int j = 0; j < 4; ++j)
                out[(size_t)(row0 + j) * NDIM + col] = acc[fm][fn][j] + bv;
        }
    }
}

extern "C" void kernel_launch(void* const* d_in, const int* in_sizes, int n_in,
                              void* d_out, int out_size, void* d_ws, size_t ws_size,
                              hipStream_t stream) {
    (void)in_sizes; (void)n_in; (void)out_size;
    const float* x = (const float*)d_in[0];
    const int* wp = (const int*)d_in[1];
    const int* wse = (const int*)d_in[2];
    const float* bias = (const float*)d_in[3];
    float* out = (float*)d_out;

    const size_t xbf_bytes = (size_t)TDIM * KDIM * 2;  // 67.1 MB
    const size_t wt_bytes = (size_t)NDIM * KDIM * 2;   // 90.2 MB

    if (ws_size >= xbf_bytes + wt_bytes) {
        unsigned short* xbf = (unsigned short*)d_ws;
        unsigned short* wt = (unsigned short*)((char*)d_ws + xbf_bytes);
        hipLaunchKernelGGL(convert_x, dim3((TDIM * KDIM) / (256 * 8)), dim3(256), 0, stream, x, xbf);
        hipLaunchKernelGGL(dequant_w, dim3(NDIM / 64, (KDIM / 8) / 64), dim3(256), 0, stream, wp, wse, wt);
        hipLaunchKernelGGL(gemm256, dim3((NDIM / 256) * (TDIM / 256)), dim3(512), 0, stream, xbf, wt, bias, out);
    } else {
        hipLaunchKernelGGL(gemm_fused, dim3(NDIM / 128, TDIM / 128), dim3(256), 0, stream, x, wp, wse, bias, out);
    }
}